// Round 3
// baseline (644.693 us; speedup 1.0000x reference)
//
#include <hip/hip_runtime.h>
#include <hip/hip_bf16.h>

// ---------------------------------------------------------------------------
// Bidirectional LSTM encoder: B=128, T=512, V=32000, E=256, H=128
// Plan:
//   k0: prep_emb   — emb fp32 -> bf16  (ws)
//   k1: prep_wt    — W_fw/W_bw [E][4H] fp32 -> Wt bf16 [n=1024][k=256] (ws)
//   k2: gemm_xw    — xw[dir][b*T+t][4H] (bf16, ws) = emb_bf16[tok] @ W   (MFMA)
//   k3: lstm_rec   — 256 blocks = (batch,dir); U column-per-thread in VGPRs
// ---------------------------------------------------------------------------

typedef short short8 __attribute__((ext_vector_type(8)));
typedef float f32x4 __attribute__((ext_vector_type(4)));

#define GLL16(g, l)                                                        \
  __builtin_amdgcn_global_load_lds(                                        \
      (const __attribute__((address_space(1))) void*)(g),                  \
      (__attribute__((address_space(3))) void*)(l), 16, 0, 0)

__device__ __forceinline__ unsigned short f2bf(float f) {
  __hip_bfloat16 h = __float2bfloat16(f);
  return __builtin_bit_cast(unsigned short, h);
}

// ---- k0: convert embedding table to bf16 ----------------------------------
__global__ void prep_emb(const float4* __restrict__ in,
                         ushort4* __restrict__ outp, int n4) {
  int i = blockIdx.x * blockDim.x + threadIdx.x;
  if (i < n4) {
    float4 v = in[i];
    ushort4 o;
    o.x = f2bf(v.x); o.y = f2bf(v.y); o.z = f2bf(v.z); o.w = f2bf(v.w);
    outp[i] = o;
  }
}

// ---- k1: build Wt bf16 [1024 n][256 k]  (n<512: fw, n>=512: bw) -----------
__global__ void prep_wt(const float* __restrict__ Wfw,
                        const float* __restrict__ Wbw,
                        __hip_bfloat16* __restrict__ Wt) {
  int n = blockIdx.x;        // 0..1023
  int k = threadIdx.x;       // 0..255
  const float* W = (n < 512) ? Wfw : Wbw;
  Wt[n * 256 + k] = __float2bfloat16(W[k * 512 + (n & 511)]);
}

// ---- k2: gathered MFMA GEMM:  xw = emb_bf16[tokens] @ W -------------------
// A: [65536][256] gathered rows (r = b*T + t -> tokens flat index r)
// B: Wt^T, tile staged as Bs[n][k]
// C: xw bf16, layout [dir][r][512]
__global__ __launch_bounds__(256) void gemm_xw(
    const int* __restrict__ tokens, const __hip_bfloat16* __restrict__ embb,
    const __hip_bfloat16* __restrict__ Wt, __hip_bfloat16* __restrict__ xw) {
  __shared__ __attribute__((aligned(16))) __hip_bfloat16 As[128 * 32];
  __shared__ __attribute__((aligned(16))) __hip_bfloat16 Bs[128 * 32];
  const int tid = threadIdx.x;
  const int bm = blockIdx.x;   // 0..511   (M tiles of 128)
  const int bn = blockIdx.y;   // 0..7     (N tiles of 128; 0..3 fw, 4..7 bw)
  const int lane = tid & 63, w = tid >> 6;

  const int ar = tid >> 2;             // staging row within 64-row pass
  const int kcol = (tid & 3) * 8;      // element offset inside 32-wide K tile
  const long r0 = (long)bm * 128 + ar;
  const int tok0 = tokens[r0];
  const int tok1 = tokens[r0 + 64];
  const __hip_bfloat16* a0 = embb + (size_t)tok0 * 256 + kcol;
  const __hip_bfloat16* a1 = embb + (size_t)tok1 * 256 + kcol;
  const __hip_bfloat16* bs0 = Wt + ((size_t)bn * 128 + ar) * 256 + kcol;
  const __hip_bfloat16* bs1 = bs0 + 64 * 256;
  __hip_bfloat16* As_d0 = As + tid * 8;
  __hip_bfloat16* As_d1 = As + 2048 + tid * 8;
  __hip_bfloat16* Bs_d0 = Bs + tid * 8;
  __hip_bfloat16* Bs_d1 = Bs + 2048 + tid * 8;

  f32x4 acc[4][4];
#pragma unroll
  for (int i = 0; i < 4; ++i)
#pragma unroll
    for (int j = 0; j < 4; ++j) acc[i][j] = (f32x4){0.f, 0.f, 0.f, 0.f};

  const int fm = (w >> 1) * 64, fn = (w & 1) * 64;  // wave 2x2 -> 64x64 tile
  const int lr = lane & 15, lk = (lane >> 4) * 8;

  for (int kk = 0; kk < 8; ++kk) {
    GLL16(a0 + kk * 32, As_d0);
    GLL16(a1 + kk * 32, As_d1);
    GLL16(bs0 + kk * 32, Bs_d0);
    GLL16(bs1 + kk * 32, Bs_d1);
    __syncthreads();
    short8 af[4], bfr[4];
#pragma unroll
    for (int i = 0; i < 4; ++i)
      af[i] = *(const short8*)(As + (fm + 16 * i + lr) * 32 + lk);
#pragma unroll
    for (int j = 0; j < 4; ++j)
      bfr[j] = *(const short8*)(Bs + (fn + 16 * j + lr) * 32 + lk);
#pragma unroll
    for (int i = 0; i < 4; ++i)
#pragma unroll
      for (int j = 0; j < 4; ++j)
        acc[i][j] = __builtin_amdgcn_mfma_f32_16x16x32_bf16(af[i], bfr[j],
                                                            acc[i][j], 0, 0, 0);
    __syncthreads();
  }

  const int orow = (lane >> 4) * 4;
#pragma unroll
  for (int i = 0; i < 4; ++i)
#pragma unroll
    for (int j = 0; j < 4; ++j)
#pragma unroll
      for (int r = 0; r < 4; ++r) {
        int row_local = fm + 16 * i + orow + r;
        int col_local = fn + 16 * j + (lane & 15);
        size_t rg = (size_t)bm * 128 + row_local;
        int ng = bn * 128 + col_local;
        size_t addr = (size_t)(ng >> 9) * 33554432ull + rg * 512 + (ng & 511);
        xw[addr] = __float2bfloat16(acc[i][j][r]);
      }
}

// ---- k3: recurrence. One block per (dir,b). Thread t owns U[:,t] in VGPRs.
__global__ __launch_bounds__(512, 2) void lstm_rec(
    const float* __restrict__ U_fw, const float* __restrict__ b_fw,
    const float* __restrict__ U_bw, const float* __restrict__ b_bw,
    const __hip_bfloat16* __restrict__ xw, float* __restrict__ out) {
  __shared__ __attribute__((aligned(16))) float h_lds[128];
  __shared__ float g_lds[512];
  const int tid = threadIdx.x;           // 0..511
  const int dir = blockIdx.x >> 7;
  const int b = blockIdx.x & 127;
  const float* U = dir ? U_bw : U_fw;
  const float bias = (dir ? b_bw : b_fw)[tid];

  float Uc[128];
#pragma unroll
  for (int k = 0; k < 128; ++k) Uc[k] = U[k * 512 + tid];

  if (tid < 128) h_lds[tid] = 0.f;
  float c = 0.f, hfin = 0.f;
  __syncthreads();

  const __hip_bfloat16* xb =
      xw + (size_t)dir * 33554432ull + (size_t)b * 262144ull + tid;
  float* outb = out + (size_t)b * 512 * 256 + dir * 128;

  int t = dir ? 511 : 0;
  const int st = dir ? -1 : 1;
  __hip_bfloat16 xc = xb[(size_t)t * 512];
  const float4* h4 = (const float4*)h_lds;
  const int grp = tid >> 7;  // 0:i 1:f 2:g 3:o  (wave-uniform)

  for (int it = 0; it < 512; ++it) {
    const int tn = (it == 511) ? t : (t + st);
    __hip_bfloat16 xn = xb[(size_t)tn * 512];  // prefetch next step
    float a0 = 0.f, a1 = 0.f, a2 = 0.f, a3 = 0.f;
#pragma unroll
    for (int k4 = 0; k4 < 32; ++k4) {
      float4 hv = h4[k4];  // LDS broadcast read
      a0 = fmaf(hv.x, Uc[4 * k4 + 0], a0);
      a1 = fmaf(hv.y, Uc[4 * k4 + 1], a1);
      a2 = fmaf(hv.z, Uc[4 * k4 + 2], a2);
      a3 = fmaf(hv.w, Uc[4 * k4 + 3], a3);
    }
    float z = __bfloat162float(xc) + bias + ((a0 + a1) + (a2 + a3));
    float act = (grp == 2) ? tanhf(z) : 1.f / (1.f + expf(-z));
    g_lds[tid] = act;
    __syncthreads();
    if (tid < 128) {
      c = g_lds[128 + tid] * c + g_lds[tid] * g_lds[256 + tid];
      float h = g_lds[384 + tid] * tanhf(c);
      hfin = h;
      h_lds[tid] = h;
      outb[(size_t)t * 256 + tid] = h;
    }
    __syncthreads();
    xc = xn;
    t = tn;
  }
  if (tid < 128) {
    float* o2 = out + 16777216;  // after [B,T,2H]
    o2[dir * 32768 + b * 128 + tid] = hfin;           // h_fw / h_bw
    o2[dir * 32768 + 16384 + b * 128 + tid] = c;      // c_fw / c_bw
  }
}

// ---------------------------------------------------------------------------
extern "C" void kernel_launch(void* const* d_in, const int* in_sizes, int n_in,
                              void* d_out, int out_size, void* d_ws,
                              size_t ws_size, hipStream_t stream) {
  const int* tokens = (const int*)d_in[0];
  const float* emb = (const float*)d_in[1];
  const float* W_fw = (const float*)d_in[2];
  const float* U_fw = (const float*)d_in[3];
  const float* b_fw = (const float*)d_in[4];
  const float* W_bw = (const float*)d_in[5];
  const float* U_bw = (const float*)d_in[6];
  const float* b_bw = (const float*)d_in[7];
  float* out = (float*)d_out;

  char* ws = (char*)d_ws;
  __hip_bfloat16* embb = (__hip_bfloat16*)(ws);               // 16,384,000 B
  __hip_bfloat16* Wt = (__hip_bfloat16*)(ws + 16384000);      //    524,288 B
  __hip_bfloat16* xw = (__hip_bfloat16*)(ws + 16908288);      // 134,217,728 B

  prep_emb<<<8000, 256, 0, stream>>>((const float4*)emb, (ushort4*)embb,
                                     2048000);
  prep_wt<<<1024, 256, 0, stream>>>(W_fw, W_bw, Wt);
  gemm_xw<<<dim3(512, 8), 256, 0, stream>>>(tokens, embb, Wt, xw);
  lstm_rec<<<256, 512, 0, stream>>>(U_fw, b_fw, U_bw, b_bw, xw, out);
}

// Round 4
// 641.478 us; speedup vs baseline: 1.0050x; 1.0050x over previous
//
#include <hip/hip_runtime.h>
#include <hip/hip_bf16.h>

// ---------------------------------------------------------------------------
// Bidirectional LSTM encoder: B=128, T=512, V=32000, E=256, H=128
//   k0: prep_emb — emb fp32 -> bf16 (ws)
//   k1: prep_wt  — W fp32 -> Wt bf16 [n=1024][k=256] (ws)
//   k2: gemm_xw  — xw[dir][b*T+t][4H] bf16 = emb_bf16[tok] @ W   (MFMA)
//   k3: prep_ut  — U fp32 -> Ut [k4][dir*512+col][4] (coalesced b128 per col)
//   k4: lstm_rec — 256 blocks = (dir,b); U column resident in 128 VGPRs
// Round-4 changes: Ut transpose + f32x4 Uc4[32] + launch_bounds(512,1)
// (round-3 VGPR=96 proved U was re-streamed from L2 every step), fast
// exp2-based activations, out-store moved after barrier-2.
// ---------------------------------------------------------------------------

typedef short short8 __attribute__((ext_vector_type(8)));
typedef float f32x4 __attribute__((ext_vector_type(4)));

#define GLL16(g, l)                                                        \
  __builtin_amdgcn_global_load_lds(                                        \
      (const __attribute__((address_space(1))) void*)(g),                  \
      (__attribute__((address_space(3))) void*)(l), 16, 0, 0)

__device__ __forceinline__ unsigned short f2bf(float f) {
  __hip_bfloat16 h = __float2bfloat16(f);
  return __builtin_bit_cast(unsigned short, h);
}

__device__ __forceinline__ float fast_sigmoid(float z) {
  return 1.f / (1.f + __expf(-z));          // z->+inf:1, z->-inf:0, NaN-free
}
__device__ __forceinline__ float fast_tanh(float z) {
  return 1.f - 2.f / (__expf(2.f * z) + 1.f);  // exact +-1 at extremes
}

// ---- k0: convert embedding table to bf16 ----------------------------------
__global__ void prep_emb(const float4* __restrict__ in,
                         ushort4* __restrict__ outp, int n4) {
  int i = blockIdx.x * blockDim.x + threadIdx.x;
  if (i < n4) {
    float4 v = in[i];
    ushort4 o;
    o.x = f2bf(v.x); o.y = f2bf(v.y); o.z = f2bf(v.z); o.w = f2bf(v.w);
    outp[i] = o;
  }
}

// ---- k1: build Wt bf16 [1024 n][256 k] ------------------------------------
__global__ void prep_wt(const float* __restrict__ Wfw,
                        const float* __restrict__ Wbw,
                        __hip_bfloat16* __restrict__ Wt) {
  int n = blockIdx.x;
  int k = threadIdx.x;
  const float* W = (n < 512) ? Wfw : Wbw;
  Wt[n * 256 + k] = __float2bfloat16(W[k * 512 + (n & 511)]);
}

// ---- k2: gathered MFMA GEMM:  xw = emb_bf16[tokens] @ W -------------------
__global__ __launch_bounds__(256) void gemm_xw(
    const int* __restrict__ tokens, const __hip_bfloat16* __restrict__ embb,
    const __hip_bfloat16* __restrict__ Wt, __hip_bfloat16* __restrict__ xw) {
  __shared__ __attribute__((aligned(16))) __hip_bfloat16 As[128 * 32];
  __shared__ __attribute__((aligned(16))) __hip_bfloat16 Bs[128 * 32];
  const int tid = threadIdx.x;
  const int bm = blockIdx.x;
  const int bn = blockIdx.y;
  const int lane = tid & 63, w = tid >> 6;

  const int ar = tid >> 2;
  const int kcol = (tid & 3) * 8;
  const long r0 = (long)bm * 128 + ar;
  const int tok0 = tokens[r0];
  const int tok1 = tokens[r0 + 64];
  const __hip_bfloat16* a0 = embb + (size_t)tok0 * 256 + kcol;
  const __hip_bfloat16* a1 = embb + (size_t)tok1 * 256 + kcol;
  const __hip_bfloat16* bs0 = Wt + ((size_t)bn * 128 + ar) * 256 + kcol;
  const __hip_bfloat16* bs1 = bs0 + 64 * 256;
  __hip_bfloat16* As_d0 = As + tid * 8;
  __hip_bfloat16* As_d1 = As + 2048 + tid * 8;
  __hip_bfloat16* Bs_d0 = Bs + tid * 8;
  __hip_bfloat16* Bs_d1 = Bs + 2048 + tid * 8;

  f32x4 acc[4][4];
#pragma unroll
  for (int i = 0; i < 4; ++i)
#pragma unroll
    for (int j = 0; j < 4; ++j) acc[i][j] = (f32x4){0.f, 0.f, 0.f, 0.f};

  const int fm = (w >> 1) * 64, fn = (w & 1) * 64;
  const int lr = lane & 15, lk = (lane >> 4) * 8;

  for (int kk = 0; kk < 8; ++kk) {
    GLL16(a0 + kk * 32, As_d0);
    GLL16(a1 + kk * 32, As_d1);
    GLL16(bs0 + kk * 32, Bs_d0);
    GLL16(bs1 + kk * 32, Bs_d1);
    __syncthreads();
    short8 af[4], bfr[4];
#pragma unroll
    for (int i = 0; i < 4; ++i)
      af[i] = *(const short8*)(As + (fm + 16 * i + lr) * 32 + lk);
#pragma unroll
    for (int j = 0; j < 4; ++j)
      bfr[j] = *(const short8*)(Bs + (fn + 16 * j + lr) * 32 + lk);
#pragma unroll
    for (int i = 0; i < 4; ++i)
#pragma unroll
      for (int j = 0; j < 4; ++j)
        acc[i][j] = __builtin_amdgcn_mfma_f32_16x16x32_bf16(af[i], bfr[j],
                                                            acc[i][j], 0, 0, 0);
    __syncthreads();
  }

  const int orow = (lane >> 4) * 4;
#pragma unroll
  for (int i = 0; i < 4; ++i)
#pragma unroll
    for (int j = 0; j < 4; ++j)
#pragma unroll
      for (int r = 0; r < 4; ++r) {
        int row_local = fm + 16 * i + orow + r;
        int col_local = fn + 16 * j + (lane & 15);
        size_t rg = (size_t)bm * 128 + row_local;
        int ng = bn * 128 + col_local;
        size_t addr = (size_t)(ng >> 9) * 33554432ull + rg * 512 + (ng & 511);
        xw[addr] = __float2bfloat16(acc[i][j][r]);
      }
}

// ---- k3: transpose U -> Ut [k4 (32)][dir*512+col (1024)][4] fp32 ----------
// lstm thread (dir,col) reads Uc4[k4] at float offset (k4*1024+dir*512+col)*4
// -> lanes consecutive = contiguous 16B: perfectly coalesced b128 loads.
__global__ void prep_ut(const float* __restrict__ Ufw,
                        const float* __restrict__ Ubw,
                        float* __restrict__ Ut) {
  int idx = blockIdx.x * 512 + threadIdx.x;  // 0..131071
  int j = idx & 3;
  int dc = (idx >> 2) & 1023;
  int k4 = idx >> 12;
  int k = 4 * k4 + j;
  int c = dc & 511;
  const float* U = (dc >> 9) ? Ubw : Ufw;
  Ut[idx] = U[k * 512 + c];
}

// ---- k4: recurrence. One block per (dir,b). U column in 128 VGPRs. --------
__global__ __launch_bounds__(512, 1) void lstm_rec(
    const float* __restrict__ Ut, const float* __restrict__ b_fw,
    const float* __restrict__ b_bw, const __hip_bfloat16* __restrict__ xw,
    float* __restrict__ out) {
  __shared__ __attribute__((aligned(16))) float h_lds[128];
  __shared__ float g_lds[512];
  const int tid = threadIdx.x;           // 0..511 (gate column)
  const int dir = blockIdx.x >> 7;
  const int b = blockIdx.x & 127;
  const float bias = (dir ? b_bw : b_fw)[tid];

  // U column resident in VGPRs: Uc4[k4] = {U[4k4+0..3][col]} (fp32)
  f32x4 Uc4[32];
#pragma unroll
  for (int k4 = 0; k4 < 32; ++k4)
    Uc4[k4] = *(const f32x4*)(Ut + ((size_t)k4 * 1024 + dir * 512 + tid) * 4);

  if (tid < 128) h_lds[tid] = 0.f;
  float c = 0.f, h = 0.f, hfin = 0.f;
  __syncthreads();

  const __hip_bfloat16* xb =
      xw + (size_t)dir * 33554432ull + (size_t)b * 262144ull + tid;
  float* outb = out + (size_t)b * 512 * 256 + dir * 128;

  int t = dir ? 511 : 0;
  const int st = dir ? -1 : 1;
  __hip_bfloat16 xc = xb[(size_t)t * 512];
  const float4* h4 = (const float4*)h_lds;
  const int grp = tid >> 7;  // 0:i 1:f 2:g 3:o (wave-uniform)

  for (int it = 0; it < 512; ++it) {
    const int tn = (it == 511) ? t : (t + st);
    __hip_bfloat16 xn = xb[(size_t)tn * 512];  // prefetch next step
    float a0 = 0.f, a1 = 0.f, a2 = 0.f, a3 = 0.f;
#pragma unroll
    for (int k4 = 0; k4 < 32; ++k4) {
      float4 hv = h4[k4];  // LDS broadcast read
      f32x4 u = Uc4[k4];
      a0 = fmaf(hv.x, u.x, a0);
      a1 = fmaf(hv.y, u.y, a1);
      a2 = fmaf(hv.z, u.z, a2);
      a3 = fmaf(hv.w, u.w, a3);
    }
    float z = __bfloat162float(xc) + bias + ((a0 + a1) + (a2 + a3));
    float act = (grp == 2) ? fast_tanh(z) : fast_sigmoid(z);
    g_lds[tid] = act;
    __syncthreads();
    if (tid < 128) {
      c = g_lds[128 + tid] * c + g_lds[tid] * g_lds[256 + tid];
      h = g_lds[384 + tid] * fast_tanh(c);
      hfin = h;
      h_lds[tid] = h;
    }
    __syncthreads();
    // out-store AFTER the barrier: overlaps next step's dot product instead
    // of being drained by the barrier's vmcnt(0).
    if (tid < 128) outb[(size_t)t * 256 + tid] = h;
    xc = xn;
    t = tn;
  }
  if (tid < 128) {
    float* o2 = out + 16777216;  // after [B,T,2H]
    o2[dir * 32768 + b * 128 + tid] = hfin;           // h_fw / h_bw
    o2[dir * 32768 + 16384 + b * 128 + tid] = c;      // c_fw / c_bw
  }
}

// ---------------------------------------------------------------------------
extern "C" void kernel_launch(void* const* d_in, const int* in_sizes, int n_in,
                              void* d_out, int out_size, void* d_ws,
                              size_t ws_size, hipStream_t stream) {
  const int* tokens = (const int*)d_in[0];
  const float* emb = (const float*)d_in[1];
  const float* W_fw = (const float*)d_in[2];
  const float* U_fw = (const float*)d_in[3];
  const float* b_fw = (const float*)d_in[4];
  const float* W_bw = (const float*)d_in[5];
  const float* U_bw = (const float*)d_in[6];
  const float* b_bw = (const float*)d_in[7];
  float* out = (float*)d_out;

  char* ws = (char*)d_ws;
  __hip_bfloat16* embb = (__hip_bfloat16*)(ws);               // 16,384,000 B
  __hip_bfloat16* Wt = (__hip_bfloat16*)(ws + 16384000);      //    524,288 B
  __hip_bfloat16* xw = (__hip_bfloat16*)(ws + 16908288);      // 134,217,728 B
  float* Ut = (float*)(ws);  // 524,288 B — overlaps embb (dead after gemm_xw)

  prep_emb<<<8000, 256, 0, stream>>>((const float4*)emb, (ushort4*)embb,
                                     2048000);
  prep_wt<<<1024, 256, 0, stream>>>(W_fw, W_bw, Wt);
  gemm_xw<<<dim3(512, 8), 256, 0, stream>>>(tokens, embb, Wt, xw);
  prep_ut<<<256, 512, 0, stream>>>(U_fw, U_bw, Ut);  // after gemm: reuses embb
  lstm_rec<<<256, 512, 0, stream>>>(Ut, b_fw, b_bw, xw, out);
}

// Round 6
// 637.510 us; speedup vs baseline: 1.0113x; 1.0062x over previous
//
#include <hip/hip_runtime.h>
#include <hip/hip_bf16.h>

// ---------------------------------------------------------------------------
// Bidirectional LSTM encoder: B=128, T=512, V=32000, E=256, H=128
//   k0: prep_emb — emb fp32 -> bf16 (ws)
//   k1: prep_wt  — W fp32 -> Wt bf16 [n=1024][k=256] (ws)
//   k2: gemm_xw  — xw[dir][b*T+t][4H] bf16 = emb_bf16[tok] @ W   (MFMA)
//   k3: prep_ut  — U fp32 -> Ut [k4][dir*512+col][4] (coalesced b128 per col)
//   k4: lstm_rec — 256 blocks = (dir,b); U column resident in 128 VGPRs
// Round-5 change (single variable): amdgpu_waves_per_eu(2,2) on lstm_rec +
// asm keep-alive anchors on Uc4. Rounds 3/4 showed VGPR_Count 96/84 — the
// allocator was spilling/sinking the U column and re-fetching 512B/thr/step
// from L2 (latency-bound, VALUBusy ~54%). Grid = 256 blocks = #CUs, so
// capping at 2 waves/EU (the 512-thread minimum) costs nothing and raises
// the VGPR budget to 256.
// ---------------------------------------------------------------------------

typedef short short8 __attribute__((ext_vector_type(8)));
typedef float f32x4 __attribute__((ext_vector_type(4)));

#define GLL16(g, l)                                                        \
  __builtin_amdgcn_global_load_lds(                                        \
      (const __attribute__((address_space(1))) void*)(g),                  \
      (__attribute__((address_space(3))) void*)(l), 16, 0, 0)

__device__ __forceinline__ unsigned short f2bf(float f) {
  __hip_bfloat16 h = __float2bfloat16(f);
  return __builtin_bit_cast(unsigned short, h);
}

__device__ __forceinline__ float fast_sigmoid(float z) {
  return 1.f / (1.f + __expf(-z));          // z->+inf:1, z->-inf:0, NaN-free
}
__device__ __forceinline__ float fast_tanh(float z) {
  return 1.f - 2.f / (__expf(2.f * z) + 1.f);  // exact +-1 at extremes
}

// ---- k0: convert embedding table to bf16 ----------------------------------
__global__ void prep_emb(const float4* __restrict__ in,
                         ushort4* __restrict__ outp, int n4) {
  int i = blockIdx.x * blockDim.x + threadIdx.x;
  if (i < n4) {
    float4 v = in[i];
    ushort4 o;
    o.x = f2bf(v.x); o.y = f2bf(v.y); o.z = f2bf(v.z); o.w = f2bf(v.w);
    outp[i] = o;
  }
}

// ---- k1: build Wt bf16 [1024 n][256 k] ------------------------------------
__global__ void prep_wt(const float* __restrict__ Wfw,
                        const float* __restrict__ Wbw,
                        __hip_bfloat16* __restrict__ Wt) {
  int n = blockIdx.x;
  int k = threadIdx.x;
  const float* W = (n < 512) ? Wfw : Wbw;
  Wt[n * 256 + k] = __float2bfloat16(W[k * 512 + (n & 511)]);
}

// ---- k2: gathered MFMA GEMM:  xw = emb_bf16[tokens] @ W -------------------
__global__ __launch_bounds__(256) void gemm_xw(
    const int* __restrict__ tokens, const __hip_bfloat16* __restrict__ embb,
    const __hip_bfloat16* __restrict__ Wt, __hip_bfloat16* __restrict__ xw) {
  __shared__ __attribute__((aligned(16))) __hip_bfloat16 As[128 * 32];
  __shared__ __attribute__((aligned(16))) __hip_bfloat16 Bs[128 * 32];
  const int tid = threadIdx.x;
  const int bm = blockIdx.x;
  const int bn = blockIdx.y;
  const int lane = tid & 63, w = tid >> 6;

  const int ar = tid >> 2;
  const int kcol = (tid & 3) * 8;
  const long r0 = (long)bm * 128 + ar;
  const int tok0 = tokens[r0];
  const int tok1 = tokens[r0 + 64];
  const __hip_bfloat16* a0 = embb + (size_t)tok0 * 256 + kcol;
  const __hip_bfloat16* a1 = embb + (size_t)tok1 * 256 + kcol;
  const __hip_bfloat16* bs0 = Wt + ((size_t)bn * 128 + ar) * 256 + kcol;
  const __hip_bfloat16* bs1 = bs0 + 64 * 256;
  __hip_bfloat16* As_d0 = As + tid * 8;
  __hip_bfloat16* As_d1 = As + 2048 + tid * 8;
  __hip_bfloat16* Bs_d0 = Bs + tid * 8;
  __hip_bfloat16* Bs_d1 = Bs + 2048 + tid * 8;

  f32x4 acc[4][4];
#pragma unroll
  for (int i = 0; i < 4; ++i)
#pragma unroll
    for (int j = 0; j < 4; ++j) acc[i][j] = (f32x4){0.f, 0.f, 0.f, 0.f};

  const int fm = (w >> 1) * 64, fn = (w & 1) * 64;
  const int lr = lane & 15, lk = (lane >> 4) * 8;

  for (int kk = 0; kk < 8; ++kk) {
    GLL16(a0 + kk * 32, As_d0);
    GLL16(a1 + kk * 32, As_d1);
    GLL16(bs0 + kk * 32, Bs_d0);
    GLL16(bs1 + kk * 32, Bs_d1);
    __syncthreads();
    short8 af[4], bfr[4];
#pragma unroll
    for (int i = 0; i < 4; ++i)
      af[i] = *(const short8*)(As + (fm + 16 * i + lr) * 32 + lk);
#pragma unroll
    for (int j = 0; j < 4; ++j)
      bfr[j] = *(const short8*)(Bs + (fn + 16 * j + lr) * 32 + lk);
#pragma unroll
    for (int i = 0; i < 4; ++i)
#pragma unroll
      for (int j = 0; j < 4; ++j)
        acc[i][j] = __builtin_amdgcn_mfma_f32_16x16x32_bf16(af[i], bfr[j],
                                                            acc[i][j], 0, 0, 0);
    __syncthreads();
  }

  const int orow = (lane >> 4) * 4;
#pragma unroll
  for (int i = 0; i < 4; ++i)
#pragma unroll
    for (int j = 0; j < 4; ++j)
#pragma unroll
      for (int r = 0; r < 4; ++r) {
        int row_local = fm + 16 * i + orow + r;
        int col_local = fn + 16 * j + (lane & 15);
        size_t rg = (size_t)bm * 128 + row_local;
        int ng = bn * 128 + col_local;
        size_t addr = (size_t)(ng >> 9) * 33554432ull + rg * 512 + (ng & 511);
        xw[addr] = __float2bfloat16(acc[i][j][r]);
      }
}

// ---- k3: transpose U -> Ut [k4 (32)][dir*512+col (1024)][4] fp32 ----------
__global__ void prep_ut(const float* __restrict__ Ufw,
                        const float* __restrict__ Ubw,
                        float* __restrict__ Ut) {
  int idx = blockIdx.x * 512 + threadIdx.x;  // 0..131071
  int j = idx & 3;
  int dc = (idx >> 2) & 1023;
  int k4 = idx >> 12;
  int k = 4 * k4 + j;
  int c = dc & 511;
  const float* U = (dc >> 9) ? Ubw : Ufw;
  Ut[idx] = U[k * 512 + c];
}

// ---- k4: recurrence. One block per (dir,b). U column in 128 VGPRs. --------
__global__ __launch_bounds__(512)
__attribute__((amdgpu_waves_per_eu(2, 2)))  // pin target: 2 waves/EU -> 256-VGPR budget
void lstm_rec(
    const float* __restrict__ Ut, const float* __restrict__ b_fw,
    const float* __restrict__ b_bw, const __hip_bfloat16* __restrict__ xw,
    float* __restrict__ out) {
  __shared__ __attribute__((aligned(16))) float h_lds[128];
  __shared__ float g_lds[512];
  const int tid = threadIdx.x;           // 0..511 (gate column)
  const int dir = blockIdx.x >> 7;
  const int b = blockIdx.x & 127;
  const float bias = (dir ? b_bw : b_fw)[tid];

  // U column resident in VGPRs: Uc4[k4] = {U[4k4+0..3][col]} (fp32)
  f32x4 Uc4[32];
#pragma unroll
  for (int k4 = 0; k4 < 32; ++k4)
    Uc4[k4] = *(const f32x4*)(Ut + ((size_t)k4 * 1024 + dir * 512 + tid) * 4);
  // Anchor the column into VGPRs before the time loop (prevents the
  // allocator from sinking the loads into the loop).
#pragma unroll
  for (int k4 = 0; k4 < 32; ++k4) asm volatile("" ::"v"(Uc4[k4]));

  if (tid < 128) h_lds[tid] = 0.f;
  float c = 0.f, h = 0.f, hfin = 0.f;
  __syncthreads();

  const __hip_bfloat16* xb =
      xw + (size_t)dir * 33554432ull + (size_t)b * 262144ull + tid;
  float* outb = out + (size_t)b * 512 * 256 + dir * 128;

  int t = dir ? 511 : 0;
  const int st = dir ? -1 : 1;
  __hip_bfloat16 xc = xb[(size_t)t * 512];
  const float4* h4 = (const float4*)h_lds;
  const int grp = tid >> 7;  // 0:i 1:f 2:g 3:o (wave-uniform)

  for (int it = 0; it < 512; ++it) {
    const int tn = (it == 511) ? t : (t + st);
    __hip_bfloat16 xn = xb[(size_t)tn * 512];  // prefetch next step
    float a0 = 0.f, a1 = 0.f, a2 = 0.f, a3 = 0.f;
#pragma unroll
    for (int k4 = 0; k4 < 32; ++k4) {
      float4 hv = h4[k4];  // LDS broadcast read
      f32x4 u = Uc4[k4];
      a0 = fmaf(hv.x, u.x, a0);
      a1 = fmaf(hv.y, u.y, a1);
      a2 = fmaf(hv.z, u.z, a2);
      a3 = fmaf(hv.w, u.w, a3);
    }
    float z = __bfloat162float(xc) + bias + ((a0 + a1) + (a2 + a3));
    float act = (grp == 2) ? fast_tanh(z) : fast_sigmoid(z);
    g_lds[tid] = act;
    __syncthreads();
    if (tid < 128) {
      c = g_lds[128 + tid] * c + g_lds[tid] * g_lds[256 + tid];
      h = g_lds[384 + tid] * fast_tanh(c);
      hfin = h;
      h_lds[tid] = h;
    }
    __syncthreads();
    if (tid < 128) outb[(size_t)t * 256 + tid] = h;
    xc = xn;
    t = tn;
  }
  if (tid < 128) {
    float* o2 = out + 16777216;  // after [B,T,2H]
    o2[dir * 32768 + b * 128 + tid] = hfin;           // h_fw / h_bw
    o2[dir * 32768 + 16384 + b * 128 + tid] = c;      // c_fw / c_bw
  }
}

// ---------------------------------------------------------------------------
extern "C" void kernel_launch(void* const* d_in, const int* in_sizes, int n_in,
                              void* d_out, int out_size, void* d_ws,
                              size_t ws_size, hipStream_t stream) {
  const int* tokens = (const int*)d_in[0];
  const float* emb = (const float*)d_in[1];
  const float* W_fw = (const float*)d_in[2];
  const float* U_fw = (const float*)d_in[3];
  const float* b_fw = (const float*)d_in[4];
  const float* W_bw = (const float*)d_in[5];
  const float* U_bw = (const float*)d_in[6];
  const float* b_bw = (const float*)d_in[7];
  float* out = (float*)d_out;

  char* ws = (char*)d_ws;
  __hip_bfloat16* embb = (__hip_bfloat16*)(ws);               // 16,384,000 B
  __hip_bfloat16* Wt = (__hip_bfloat16*)(ws + 16384000);      //    524,288 B
  __hip_bfloat16* xw = (__hip_bfloat16*)(ws + 16908288);      // 134,217,728 B
  float* Ut = (float*)(ws);  // 524,288 B — overlaps embb (dead after gemm_xw)

  prep_emb<<<8000, 256, 0, stream>>>((const float4*)emb, (ushort4*)embb,
                                     2048000);
  prep_wt<<<1024, 256, 0, stream>>>(W_fw, W_bw, Wt);
  gemm_xw<<<dim3(512, 8), 256, 0, stream>>>(tokens, embb, Wt, xw);
  prep_ut<<<256, 512, 0, stream>>>(U_fw, U_bw, Ut);  // after gemm: reuses embb
  lstm_rec<<<256, 512, 0, stream>>>(Ut, b_fw, b_bw, xw, out);
}

// Round 8
// 633.373 us; speedup vs baseline: 1.0179x; 1.0065x over previous
//
#include <hip/hip_runtime.h>
#include <hip/hip_bf16.h>

// ---------------------------------------------------------------------------
// Bidirectional LSTM encoder: B=128, T=512, V=32000, E=256, H=128
//   k0: prep_emb — emb fp32 -> bf16 (ws)
//   k1: prep_wt  — W fp32 -> Wt bf16 [n=1024][k=256] (ws)
//   k2: gemm_xw  — xw[dir][b*T+t][4H] bf16 = emb_bf16[tok] @ W   (MFMA)
//   k3: prep_ut  — U fp32 -> Ut [k4][dir*512+col][4] (coalesced b128 per col)
//   k4: lstm_rec — 256 blocks = (dir,b); U column resident in 128 VGPRs
// Round-7 change (single variable): U column loaded via inline-asm
// global_load_dwordx4 -> outputs are opaque asm results the compiler CANNOT
// rematerialize/sink into the loop (rounds 3-6: VGPR_Count 96/84/88 proved
// plain loads get re-issued from L2 every step ~2500cyc/step). vmcnt(0) +
// sched_barrier(0) fence per guide rule #18. waves_per_eu(2,2) kept: 256-VGPR
// budget so the ~170 live regs fit without scratch.
// ---------------------------------------------------------------------------

typedef short short8 __attribute__((ext_vector_type(8)));
typedef float f32x4 __attribute__((ext_vector_type(4)));

#define GLL16(g, l)                                                        \
  __builtin_amdgcn_global_load_lds(                                        \
      (const __attribute__((address_space(1))) void*)(g),                  \
      (__attribute__((address_space(3))) void*)(l), 16, 0, 0)

__device__ __forceinline__ unsigned short f2bf(float f) {
  __hip_bfloat16 h = __float2bfloat16(f);
  return __builtin_bit_cast(unsigned short, h);
}

__device__ __forceinline__ float fast_sigmoid(float z) {
  return 1.f / (1.f + __expf(-z));          // z->+inf:1, z->-inf:0, NaN-free
}
__device__ __forceinline__ float fast_tanh(float z) {
  return 1.f - 2.f / (__expf(2.f * z) + 1.f);  // exact +-1 at extremes
}

// ---- k0: convert embedding table to bf16 ----------------------------------
__global__ void prep_emb(const float4* __restrict__ in,
                         ushort4* __restrict__ outp, int n4) {
  int i = blockIdx.x * blockDim.x + threadIdx.x;
  if (i < n4) {
    float4 v = in[i];
    ushort4 o;
    o.x = f2bf(v.x); o.y = f2bf(v.y); o.z = f2bf(v.z); o.w = f2bf(v.w);
    outp[i] = o;
  }
}

// ---- k1: build Wt bf16 [1024 n][256 k] ------------------------------------
__global__ void prep_wt(const float* __restrict__ Wfw,
                        const float* __restrict__ Wbw,
                        __hip_bfloat16* __restrict__ Wt) {
  int n = blockIdx.x;
  int k = threadIdx.x;
  const float* W = (n < 512) ? Wfw : Wbw;
  Wt[n * 256 + k] = __float2bfloat16(W[k * 512 + (n & 511)]);
}

// ---- k2: gathered MFMA GEMM:  xw = emb_bf16[tokens] @ W -------------------
__global__ __launch_bounds__(256) void gemm_xw(
    const int* __restrict__ tokens, const __hip_bfloat16* __restrict__ embb,
    const __hip_bfloat16* __restrict__ Wt, __hip_bfloat16* __restrict__ xw) {
  __shared__ __attribute__((aligned(16))) __hip_bfloat16 As[128 * 32];
  __shared__ __attribute__((aligned(16))) __hip_bfloat16 Bs[128 * 32];
  const int tid = threadIdx.x;
  const int bm = blockIdx.x;
  const int bn = blockIdx.y;
  const int lane = tid & 63, w = tid >> 6;

  const int ar = tid >> 2;
  const int kcol = (tid & 3) * 8;
  const long r0 = (long)bm * 128 + ar;
  const int tok0 = tokens[r0];
  const int tok1 = tokens[r0 + 64];
  const __hip_bfloat16* a0 = embb + (size_t)tok0 * 256 + kcol;
  const __hip_bfloat16* a1 = embb + (size_t)tok1 * 256 + kcol;
  const __hip_bfloat16* bs0 = Wt + ((size_t)bn * 128 + ar) * 256 + kcol;
  const __hip_bfloat16* bs1 = bs0 + 64 * 256;
  __hip_bfloat16* As_d0 = As + tid * 8;
  __hip_bfloat16* As_d1 = As + 2048 + tid * 8;
  __hip_bfloat16* Bs_d0 = Bs + tid * 8;
  __hip_bfloat16* Bs_d1 = Bs + 2048 + tid * 8;

  f32x4 acc[4][4];
#pragma unroll
  for (int i = 0; i < 4; ++i)
#pragma unroll
    for (int j = 0; j < 4; ++j) acc[i][j] = (f32x4){0.f, 0.f, 0.f, 0.f};

  const int fm = (w >> 1) * 64, fn = (w & 1) * 64;
  const int lr = lane & 15, lk = (lane >> 4) * 8;

  for (int kk = 0; kk < 8; ++kk) {
    GLL16(a0 + kk * 32, As_d0);
    GLL16(a1 + kk * 32, As_d1);
    GLL16(bs0 + kk * 32, Bs_d0);
    GLL16(bs1 + kk * 32, Bs_d1);
    __syncthreads();
    short8 af[4], bfr[4];
#pragma unroll
    for (int i = 0; i < 4; ++i)
      af[i] = *(const short8*)(As + (fm + 16 * i + lr) * 32 + lk);
#pragma unroll
    for (int j = 0; j < 4; ++j)
      bfr[j] = *(const short8*)(Bs + (fn + 16 * j + lr) * 32 + lk);
#pragma unroll
    for (int i = 0; i < 4; ++i)
#pragma unroll
      for (int j = 0; j < 4; ++j)
        acc[i][j] = __builtin_amdgcn_mfma_f32_16x16x32_bf16(af[i], bfr[j],
                                                            acc[i][j], 0, 0, 0);
    __syncthreads();
  }

  const int orow = (lane >> 4) * 4;
#pragma unroll
  for (int i = 0; i < 4; ++i)
#pragma unroll
    for (int j = 0; j < 4; ++j)
#pragma unroll
      for (int r = 0; r < 4; ++r) {
        int row_local = fm + 16 * i + orow + r;
        int col_local = fn + 16 * j + (lane & 15);
        size_t rg = (size_t)bm * 128 + row_local;
        int ng = bn * 128 + col_local;
        size_t addr = (size_t)(ng >> 9) * 33554432ull + rg * 512 + (ng & 511);
        xw[addr] = __float2bfloat16(acc[i][j][r]);
      }
}

// ---- k3: transpose U -> Ut [k4 (32)][dir*512+col (1024)][4] fp32 ----------
__global__ void prep_ut(const float* __restrict__ Ufw,
                        const float* __restrict__ Ubw,
                        float* __restrict__ Ut) {
  int idx = blockIdx.x * 512 + threadIdx.x;  // 0..131071
  int j = idx & 3;
  int dc = (idx >> 2) & 1023;
  int k4 = idx >> 12;
  int k = 4 * k4 + j;
  int c = dc & 511;
  const float* U = (dc >> 9) ? Ubw : Ufw;
  Ut[idx] = U[k * 512 + c];
}

// ---- k4: recurrence. One block per (dir,b). U column in 128 VGPRs. --------
__global__ __launch_bounds__(512)
__attribute__((amdgpu_waves_per_eu(2, 2)))  // 2 waves/EU target -> 256-VGPR budget
void lstm_rec(
    const float* __restrict__ Ut, const float* __restrict__ b_fw,
    const float* __restrict__ b_bw, const __hip_bfloat16* __restrict__ xw,
    float* __restrict__ out) {
  __shared__ __attribute__((aligned(16))) float h_lds[128];
  __shared__ float g_lds[512];
  const int tid = threadIdx.x;           // 0..511 (gate column)
  const int dir = blockIdx.x >> 7;
  const int b = blockIdx.x & 127;
  const float bias = (dir ? b_bw : b_fw)[tid];

  // U column forced into VGPRs via inline-asm loads: asm outputs cannot be
  // rematerialized/sunk into the loop by the compiler (rounds 3-6 failure
  // mode). 32 x f32x4 = 128 VGPRs resident for the whole time loop.
  f32x4 Uc4[32];
#pragma unroll
  for (int k4 = 0; k4 < 32; ++k4) {
    const float* p = Ut + ((size_t)k4 * 1024 + dir * 512 + tid) * 4;
    asm volatile("global_load_dwordx4 %0, %1, off"
                 : "=v"(Uc4[k4])
                 : "v"(p)
                 : "memory");
  }
  asm volatile("s_waitcnt vmcnt(0)" ::: "memory");
  __builtin_amdgcn_sched_barrier(0);  // rule #18: block hoisting past waitcnt

  if (tid < 128) h_lds[tid] = 0.f;
  float c = 0.f, h = 0.f, hfin = 0.f;
  __syncthreads();

  const __hip_bfloat16* xb =
      xw + (size_t)dir * 33554432ull + (size_t)b * 262144ull + tid;
  float* outb = out + (size_t)b * 512 * 256 + dir * 128;

  int t = dir ? 511 : 0;
  const int st = dir ? -1 : 1;
  __hip_bfloat16 xc = xb[(size_t)t * 512];
  const float4* h4 = (const float4*)h_lds;
  const int grp = tid >> 7;  // 0:i 1:f 2:g 3:o (wave-uniform)

  for (int it = 0; it < 512; ++it) {
    const int tn = (it == 511) ? t : (t + st);
    __hip_bfloat16 xn = xb[(size_t)tn * 512];  // prefetch next step
    float a0 = 0.f, a1 = 0.f, a2 = 0.f, a3 = 0.f;
#pragma unroll
    for (int k4 = 0; k4 < 32; ++k4) {
      float4 hv = h4[k4];  // LDS broadcast read
      f32x4 u = Uc4[k4];
      a0 = fmaf(hv.x, u.x, a0);
      a1 = fmaf(hv.y, u.y, a1);
      a2 = fmaf(hv.z, u.z, a2);
      a3 = fmaf(hv.w, u.w, a3);
    }
    float z = __bfloat162float(xc) + bias + ((a0 + a1) + (a2 + a3));
    float act = (grp == 2) ? fast_tanh(z) : fast_sigmoid(z);
    g_lds[tid] = act;
    __syncthreads();
    if (tid < 128) {
      c = g_lds[128 + tid] * c + g_lds[tid] * g_lds[256 + tid];
      h = g_lds[384 + tid] * fast_tanh(c);
      hfin = h;
      h_lds[tid] = h;
    }
    __syncthreads();
    if (tid < 128) outb[(size_t)t * 256 + tid] = h;
    xc = xn;
    t = tn;
  }
  if (tid < 128) {
    float* o2 = out + 16777216;  // after [B,T,2H]
    o2[dir * 32768 + b * 128 + tid] = hfin;           // h_fw / h_bw
    o2[dir * 32768 + 16384 + b * 128 + tid] = c;      // c_fw / c_bw
  }
}

// ---------------------------------------------------------------------------
extern "C" void kernel_launch(void* const* d_in, const int* in_sizes, int n_in,
                              void* d_out, int out_size, void* d_ws,
                              size_t ws_size, hipStream_t stream) {
  const int* tokens = (const int*)d_in[0];
  const float* emb = (const float*)d_in[1];
  const float* W_fw = (const float*)d_in[2];
  const float* U_fw = (const float*)d_in[3];
  const float* b_fw = (const float*)d_in[4];
  const float* W_bw = (const float*)d_in[5];
  const float* U_bw = (const float*)d_in[6];
  const float* b_bw = (const float*)d_in[7];
  float* out = (float*)d_out;

  char* ws = (char*)d_ws;
  __hip_bfloat16* embb = (__hip_bfloat16*)(ws);               // 16,384,000 B
  __hip_bfloat16* Wt = (__hip_bfloat16*)(ws + 16384000);      //    524,288 B
  __hip_bfloat16* xw = (__hip_bfloat16*)(ws + 16908288);      // 134,217,728 B
  float* Ut = (float*)(ws);  // 524,288 B — overlaps embb (dead after gemm_xw)

  prep_emb<<<8000, 256, 0, stream>>>((const float4*)emb, (ushort4*)embb,
                                     2048000);
  prep_wt<<<1024, 256, 0, stream>>>(W_fw, W_bw, Wt);
  gemm_xw<<<dim3(512, 8), 256, 0, stream>>>(tokens, embb, Wt, xw);
  prep_ut<<<256, 512, 0, stream>>>(U_fw, U_bw, Ut);  // after gemm: reuses embb
  lstm_rec<<<256, 512, 0, stream>>>(Ut, b_fw, b_bw, xw, out);
}